// Round 17
// baseline (63.077 us; speedup 1.0000x reference)
//
#include <hip/hip_runtime.h>
#include <cstddef>
#include <cstdint>

#define D_MODEL 512
#define DK 64
#define LQ 1024
#define LK 1024
#define NB 2
#define LN_EPS 1e-6f
#define L2E2 2.8853900817779268f  // 2*log2(e)

// ---------------- projections ----------------
// type 0: qp=q@Wq -> ab4[row][dp] = float4{A_dp, B_dp, A_dp+32, B_dp+32}
//         with A = v_d*e^{-2qp}, B = e^{-2qp}
// type 1: ek=e^{2*(k@Wk)} -> ekT2[batch][dp][j] = float2{ek[dp], ek[dp+32]}
// type 2: vp = v@Wv (f32 row-major)
// r16 lesson (arithmetic): old mapping issued 512 ds_read_b128/thread ->
// 15.4us of serialized LDS pipe (matches measured proj). New mapping:
// thread = (row, col-quad): one b128 row-read feeds 16 fma (4e x 4cols),
// ds_reads drop 4x; W via coalesced float4 VMEM (separate pipe).
// 128 thr (2 waves), 8 rows/block, grid 768 = exactly 3 blocks/CU.
#define PR_ROWS 8
__global__ __launch_bounds__(128, 4) void proj_kernel(
    const float* __restrict__ q, const float* __restrict__ k,
    const float* __restrict__ v, const float* __restrict__ Wq,
    const float* __restrict__ Wk, const float* __restrict__ Wv,
    const float* __restrict__ v_param, float4* __restrict__ ab4,
    float2* __restrict__ ekT2, float* __restrict__ vp) {
  __shared__ float rows[PR_ROWS][D_MODEL];  // 16 KB
  __shared__ float stA[PR_ROWS][DK];        // 2 KB (A or ek)
  __shared__ float stB[PR_ROWS][DK];        // 2 KB (B)
  const int tid = threadIdx.x;       // 0..127
  const int type = blockIdx.x >> 8;  // 256 row-groups per type
  const int r0 = (blockIdx.x & 255) * PR_ROWS;
  const float* __restrict__ in = (type == 0) ? q : (type == 1) ? k : v;
  const float* __restrict__ W = (type == 0) ? Wq : (type == 1) ? Wk : Wv;
  {
    const float4* __restrict__ in4 = (const float4*)(in + (size_t)r0 * D_MODEL);
    float4* r4 = (float4*)&rows[0][0];
#pragma unroll
    for (int t = 0; t < 8; ++t) r4[tid + 128 * t] = in4[tid + 128 * t];
  }
  __syncthreads();
  const int r = tid >> 4;    // 0..7: this thread's row
  const int qd = tid & 15;   // col quad: cols 4qd..4qd+3
  const float4* __restrict__ W4 = (const float4*)W;  // [512][16] float4
  float4 a0 = make_float4(0.f, 0.f, 0.f, 0.f);
  float4 a1 = make_float4(0.f, 0.f, 0.f, 0.f);
#pragma unroll 4
  for (int e = 0; e < D_MODEL; e += 4) {
    float4 x = *(const float4*)&rows[r][e];  // 1 b128 -> 16 fma
    float4 w0 = W4[(size_t)(e + 0) * 16 + qd];
    float4 w1 = W4[(size_t)(e + 1) * 16 + qd];
    float4 w2 = W4[(size_t)(e + 2) * 16 + qd];
    float4 w3 = W4[(size_t)(e + 3) * 16 + qd];
    a0.x = fmaf(x.x, w0.x, a0.x); a0.y = fmaf(x.x, w0.y, a0.y);
    a0.z = fmaf(x.x, w0.z, a0.z); a0.w = fmaf(x.x, w0.w, a0.w);
    a1.x = fmaf(x.y, w1.x, a1.x); a1.y = fmaf(x.y, w1.y, a1.y);
    a1.z = fmaf(x.y, w1.z, a1.z); a1.w = fmaf(x.y, w1.w, a1.w);
    a0.x = fmaf(x.z, w2.x, a0.x); a0.y = fmaf(x.z, w2.y, a0.y);
    a0.z = fmaf(x.z, w2.z, a0.z); a0.w = fmaf(x.z, w2.w, a0.w);
    a1.x = fmaf(x.w, w3.x, a1.x); a1.y = fmaf(x.w, w3.y, a1.y);
    a1.z = fmaf(x.w, w3.z, a1.z); a1.w = fmaf(x.w, w3.w, a1.w);
  }
  float4 acc = make_float4(a0.x + a1.x, a0.y + a1.y, a0.z + a1.z, a0.w + a1.w);
  const int c0 = qd * 4;
  if (type == 2) {
    *(float4*)&vp[(size_t)(r0 + r) * DK + c0] = acc;
  } else if (type == 0) {
    float4 vp4 = *(const float4*)&v_param[c0];
    float i0 = __builtin_amdgcn_exp2f(-L2E2 * acc.x);
    float i1 = __builtin_amdgcn_exp2f(-L2E2 * acc.y);
    float i2 = __builtin_amdgcn_exp2f(-L2E2 * acc.z);
    float i3 = __builtin_amdgcn_exp2f(-L2E2 * acc.w);
    stA[r][c0 + 0] = vp4.x * i0; stB[r][c0 + 0] = i0;
    stA[r][c0 + 1] = vp4.y * i1; stB[r][c0 + 1] = i1;
    stA[r][c0 + 2] = vp4.z * i2; stB[r][c0 + 2] = i2;
    stA[r][c0 + 3] = vp4.w * i3; stB[r][c0 + 3] = i3;
    __syncthreads();
#pragma unroll
    for (int s = 0; s < 2; ++s) {
      int ent = tid + 128 * s;          // 256 entries: 8 rows x 32 dp
      int row = ent >> 5, dp = ent & 31;
      ab4[(size_t)(r0 + row) * 32 + dp] =
          make_float4(stA[row][dp], stB[row][dp],
                      stA[row][dp + 32], stB[row][dp + 32]);
    }
  } else {
    stA[r][c0 + 0] = __builtin_amdgcn_exp2f(L2E2 * acc.x);
    stA[r][c0 + 1] = __builtin_amdgcn_exp2f(L2E2 * acc.y);
    stA[r][c0 + 2] = __builtin_amdgcn_exp2f(L2E2 * acc.z);
    stA[r][c0 + 3] = __builtin_amdgcn_exp2f(L2E2 * acc.w);
    __syncthreads();
    const int b = r0 >> 10, j0 = r0 & 1023;
#pragma unroll
    for (int s = 0; s < 2; ++s) {
      int ent = tid + 128 * s;          // 256 entries: 32 dp x 8 j
      int dp = ent >> 3, jj = ent & 7;
      ekT2[(size_t)b * 32 * LK + (size_t)dp * LK + j0 + jj] =
          make_float2(stA[jj][dp], stA[jj][dp + 32]);
    }
  }
}

// ---------------- fused scores + softmax + PV + FC + LN ----------------
// r16-proven: 256 thr (4 waves), RB=2 rows/block, grid 1024. Score: zero
// LDS, wave-uniform A/B s_loads, quad-rcp, f32 K, 4 consecutive j/thread.
#define RB 2
__global__ __launch_bounds__(256, 6) void attn_kernel(
    const float4* __restrict__ ab4, const float2* __restrict__ ekT2,
    const float* __restrict__ vp, const float* __restrict__ resid,
    const float* __restrict__ Wfc, const float* __restrict__ gamma,
    const float* __restrict__ beta, float* __restrict__ out,
    float* __restrict__ attn_out) {
  __shared__ float sc[RB][LK];                  // 8 KB P rows
  __shared__ float4 pvred[4][RB][16];           // 2 KB PV partials
  __shared__ __align__(16) float ovlT[DK][RB];  // 0.5 KB, e-major
  __shared__ float red[2][RB][4];               // LN reductions
  __shared__ float mred[RB][4], sred[RB][4];
  const int tid = threadIdx.x;
  const int row0 = blockIdx.x * RB;  // RB | LQ -> single batch per block
  const int batch = row0 >> 10;
  const float2* __restrict__ ekT_b = ekT2 + (size_t)batch * 32 * LK;
  const float* __restrict__ vp_b = vp + (size_t)batch * LK * DK;
  const float4* __restrict__ abr0 = ab4 + (size_t)(row0 + 0) * 32;
  const float4* __restrict__ abr1 = ab4 + (size_t)(row0 + 1) * 32;

  float a0[4] = {0.f, 0.f, 0.f, 0.f};  // [jj] row 0, static-indexed
  float a1[4] = {0.f, 0.f, 0.f, 0.f};

#pragma unroll
  for (int qd = 0; qd < 16; ++qd) {  // quad covers dp = 2qd, 2qd+1
    const float4* e0 =
        (const float4*)(ekT_b + (size_t)(2 * qd + 0) * LK + 4 * tid);
    const float4* e1 =
        (const float4*)(ekT_b + (size_t)(2 * qd + 1) * LK + 4 * tid);
    float4 ka = e0[0], kb = e0[1];  // (j0,j1) , (j2,j3) for row dp
    float4 kc = e1[0], kd = e1[1];  // same for row dp+1
    float2 k0[4], k1[4];
    k0[0] = make_float2(ka.x, ka.y); k0[1] = make_float2(ka.z, ka.w);
    k0[2] = make_float2(kb.x, kb.y); k0[3] = make_float2(kb.z, kb.w);
    k1[0] = make_float2(kc.x, kc.y); k1[1] = make_float2(kc.z, kc.w);
    k1[2] = make_float2(kd.x, kd.y); k1[3] = make_float2(kd.z, kd.w);
    float4 P0 = abr0[2 * qd], Q0 = abr0[2 * qd + 1];
    float4 P1 = abr1[2 * qd], Q1 = abr1[2 * qd + 1];
#pragma unroll
    for (int jj = 0; jj < 4; ++jj) {
#define QUAD(PP, QQ, ACC)                                                  \
  {                                                                        \
    float x1 = k0[jj].x + PP.y, x2 = k0[jj].y + PP.w;                      \
    float x3 = k1[jj].x + QQ.y, x4 = k1[jj].y + QQ.w;                      \
    float p12 = x1 * x2, p34 = x3 * x4;                                    \
    float n12 = fmaf(PP.z, x1, PP.x * x2);                                 \
    float n34 = fmaf(QQ.z, x3, QQ.x * x4);                                 \
    float num = fmaf(n34, p12, n12 * p34);                                 \
    ACC[jj] = fmaf(num, __builtin_amdgcn_rcpf(p12 * p34), ACC[jj]);        \
  }
      QUAD(P0, Q0, a0)
      QUAD(P1, Q1, a1)
#undef QUAD
    }
  }

  const int wave = __builtin_amdgcn_readfirstlane(tid >> 6);
  const int lane = tid & 63;

  // softmax over score = C - 2*acc -> shift by min(acc)
  {
    float pm0 = fminf(fminf(a0[0], a0[1]), fminf(a0[2], a0[3]));
    float pm1 = fminf(fminf(a1[0], a1[1]), fminf(a1[2], a1[3]));
#pragma unroll
    for (int off = 32; off > 0; off >>= 1) {
      pm0 = fminf(pm0, __shfl_xor(pm0, off));
      pm1 = fminf(pm1, __shfl_xor(pm1, off));
    }
    if (lane == 0) {
      mred[0][wave] = pm0;
      mred[1][wave] = pm1;
    }
    __syncthreads();
    float m0 = fminf(fminf(mred[0][0], mred[0][1]), fminf(mred[0][2], mred[0][3]));
    float m1 = fminf(fminf(mred[1][0], mred[1][1]), fminf(mred[1][2], mred[1][3]));
    float s0 = 0.f, s1 = 0.f;
#pragma unroll
    for (int jj = 0; jj < 4; ++jj) {
      a0[jj] = __builtin_amdgcn_exp2f((m0 - a0[jj]) * L2E2); s0 += a0[jj];
      a1[jj] = __builtin_amdgcn_exp2f((m1 - a1[jj]) * L2E2); s1 += a1[jj];
    }
#pragma unroll
    for (int off = 32; off > 0; off >>= 1) {
      s0 += __shfl_xor(s0, off);
      s1 += __shfl_xor(s1, off);
    }
    if (lane == 0) {
      sred[0][wave] = s0;
      sred[1][wave] = s1;
    }
    __syncthreads();
    float i0 = __builtin_amdgcn_rcpf(sred[0][0] + sred[0][1] + sred[0][2] + sred[0][3]);
    float i1 = __builtin_amdgcn_rcpf(sred[1][0] + sred[1][1] + sred[1][2] + sred[1][3]);
    float4 p0 = make_float4(a0[0] * i0, a0[1] * i0, a0[2] * i0, a0[3] * i0);
    float4 p1 = make_float4(a1[0] * i1, a1[1] * i1, a1[2] * i1, a1[3] * i1);
    *(float4*)&sc[0][4 * tid] = p0;
    *(float4*)&sc[1][4 * tid] = p1;
    *(float4*)(attn_out + (size_t)(row0 + 0) * LK + 4 * tid) = p0;
    *(float4*)(attn_out + (size_t)(row0 + 1) * LK + 4 * tid) = p1;
  }
  __syncthreads();

  // PV: wave owns 256-j slice; vp read once per block per j (serves 2 rows)
  {
    const int jj = lane >> 4, l16 = lane & 15;
    const float4* __restrict__ vp4 = (const float4*)vp_b;
    float4 a[RB];
#pragma unroll
    for (int r = 0; r < RB; ++r) a[r] = make_float4(0.f, 0.f, 0.f, 0.f);
#pragma unroll 4
    for (int it = 0; it < 64; ++it) {
      int j = (wave << 8) + (it << 2) + jj;
      float4 vv = vp4[(size_t)j * (DK / 4) + l16];
#pragma unroll
      for (int r = 0; r < RB; ++r) {
        float pw = sc[r][j];
        a[r].x = fmaf(pw, vv.x, a[r].x);
        a[r].y = fmaf(pw, vv.y, a[r].y);
        a[r].z = fmaf(pw, vv.z, a[r].z);
        a[r].w = fmaf(pw, vv.w, a[r].w);
      }
    }
#pragma unroll
    for (int r = 0; r < RB; ++r) {
      a[r].x += __shfl_xor(a[r].x, 16); a[r].y += __shfl_xor(a[r].y, 16);
      a[r].z += __shfl_xor(a[r].z, 16); a[r].w += __shfl_xor(a[r].w, 16);
      a[r].x += __shfl_xor(a[r].x, 32); a[r].y += __shfl_xor(a[r].y, 32);
      a[r].z += __shfl_xor(a[r].z, 32); a[r].w += __shfl_xor(a[r].w, 32);
    }
    if (jj == 0) {
#pragma unroll
      for (int r = 0; r < RB; ++r) pvred[wave][r][l16] = a[r];
    }
  }
  __syncthreads();
  if (tid < 32) {  // final PV reduce -> transposed ovlT[e][r]
    int r = tid >> 4, l16 = tid & 15;
    float4 s = make_float4(0.f, 0.f, 0.f, 0.f);
#pragma unroll
    for (int w = 0; w < 4; ++w) {
      float4 t = pvred[w][r][l16];
      s.x += t.x; s.y += t.y; s.z += t.z; s.w += t.w;
    }
    ovlT[l16 * 4 + 0][r] = s.x;
    ovlT[l16 * 4 + 1][r] = s.y;
    ovlT[l16 * 4 + 2][r] = s.z;
    ovlT[l16 * 4 + 3][r] = s.w;
  }
  __syncthreads();

  // FC + residual + LN: thread owns columns c, c+256 of 2 rows
  {
    const int c0 = tid, c1 = tid + 256;
    float y[RB][2];
#pragma unroll
    for (int r = 0; r < RB; ++r) {
      y[r][0] = resid[(size_t)(row0 + r) * D_MODEL + c0];
      y[r][1] = resid[(size_t)(row0 + r) * D_MODEL + c1];
    }
#pragma unroll 4
    for (int e = 0; e < DK; ++e) {
      float w0 = Wfc[(size_t)e * D_MODEL + c0];
      float w1 = Wfc[(size_t)e * D_MODEL + c1];
      float2 ov = *(const float2*)&ovlT[e][0];
      y[0][0] = fmaf(ov.x, w0, y[0][0]); y[0][1] = fmaf(ov.x, w1, y[0][1]);
      y[1][0] = fmaf(ov.y, w0, y[1][0]); y[1][1] = fmaf(ov.y, w1, y[1][1]);
    }
#pragma unroll
    for (int r = 0; r < RB; ++r) {
      float s = y[r][0] + y[r][1];
#pragma unroll
      for (int off = 32; off > 0; off >>= 1) s += __shfl_xor(s, off);
      if (lane == 0) red[0][r][wave] = s;
    }
    __syncthreads();
    float mu[RB];
#pragma unroll
    for (int r = 0; r < RB; ++r)
      mu[r] = (red[0][r][0] + red[0][r][1] + red[0][r][2] + red[0][r][3]) *
              (1.0f / D_MODEL);
#pragma unroll
    for (int r = 0; r < RB; ++r) {
      float d0 = y[r][0] - mu[r], d1 = y[r][1] - mu[r];
      float s = d0 * d0 + d1 * d1;
#pragma unroll
      for (int off = 32; off > 0; off >>= 1) s += __shfl_xor(s, off);
      if (lane == 0) red[1][r][wave] = s;
    }
    __syncthreads();
    float g0 = gamma[c0], g1 = gamma[c1], b0 = beta[c0], b1 = beta[c1];
#pragma unroll
    for (int r = 0; r < RB; ++r) {
      float var = (red[1][r][0] + red[1][r][1] + red[1][r][2] + red[1][r][3]) *
                  (1.0f / D_MODEL);
      float rstd = rsqrtf(var + LN_EPS);
      out[(size_t)(row0 + r) * D_MODEL + c0] = (y[r][0] - mu[r]) * rstd * g0 + b0;
      out[(size_t)(row0 + r) * D_MODEL + c1] = (y[r][1] - mu[r]) * rstd * g1 + b1;
    }
  }
}

extern "C" void kernel_launch(void* const* d_in, const int* in_sizes, int n_in,
                              void* d_out, int out_size, void* d_ws,
                              size_t ws_size, hipStream_t stream) {
  const float* q = (const float*)d_in[0];
  const float* k = (const float*)d_in[1];
  const float* v = (const float*)d_in[2];
  const float* Wq = (const float*)d_in[3];
  const float* Wk = (const float*)d_in[4];
  const float* Wv = (const float*)d_in[5];
  const float* v_param = (const float*)d_in[6];
  const float* Wfc = (const float*)d_in[7];
  const float* gamma = (const float*)d_in[8];
  const float* beta = (const float*)d_in[9];

  float* out = (float*)d_out;                     // [B*LQ*D_MODEL]
  float* attn = out + (size_t)NB * LQ * D_MODEL;  // [B*LQ*LK]

  float* base = (float*)d_ws;
  float4* ab4 = (float4*)base;                    // 2048*32 float4 (1 MB)
  float* p1 = base + (size_t)NB * LQ * 32 * 4;    // floats consumed by ab4
  float2* ekT2 = (float2*)p1;                     // 2*32*1024 float2 (512 KB)
  float* vp = p1 + (size_t)NB * 32 * LK * 2;      // [2048*64]

  hipLaunchKernelGGL(proj_kernel, dim3(3 * 256), dim3(128), 0, stream, q, k, v,
                     Wq, Wk, Wv, v_param, ab4, ekT2, vp);
  hipLaunchKernelGGL(attn_kernel, dim3(NB * LQ / RB), dim3(256), 0, stream,
                     ab4, ekT2, vp, q, Wfc, gamma, beta, out, attn);
}

// Round 18
// 54.995 us; speedup vs baseline: 1.1470x; 1.1470x over previous
//
#include <hip/hip_runtime.h>
#include <cstddef>
#include <cstdint>

#define D_MODEL 512
#define DK 64
#define LQ 1024
#define LK 1024
#define NB 2
#define LN_EPS 1e-6f
#define L2E2 2.8853900817779268f  // 2*log2(e)

// ---------------- projections ---------------- (r13-proven, 53.9us config)
// type 0: qp=q@Wq -> ab4[row][dp] = float4{A_dp, B_dp, A_dp+32, B_dp+32}
//         with A = v_d*e^{-2qp}, B = e^{-2qp}
// type 1: ek=e^{2*(k@Wk)} -> ekT2[batch][dp][j] = float2{ek[dp], ek[dp+32]}
// type 2: vp = v@Wv (f32 row-major)
// 256 thr (4 waves), 16 rows/block (4/wave), grid 384.
#define PR_ROWS 16
__global__ __launch_bounds__(256, 4) void proj_kernel(
    const float* __restrict__ q, const float* __restrict__ k,
    const float* __restrict__ v, const float* __restrict__ Wq,
    const float* __restrict__ Wk, const float* __restrict__ Wv,
    const float* __restrict__ v_param, float4* __restrict__ ab4,
    float2* __restrict__ ekT2, float* __restrict__ vp) {
  __shared__ float rows[PR_ROWS][D_MODEL];  // 32 KB
  const int tid = threadIdx.x;
  const int type = blockIdx.x >> 7;  // 128 row-groups per type
  const int r0 = (blockIdx.x & 127) * PR_ROWS;
  const float* __restrict__ in = (type == 0) ? q : (type == 1) ? k : v;
  const float* __restrict__ W = (type == 0) ? Wq : (type == 1) ? Wk : Wv;
  {
    const float4* __restrict__ in4 = (const float4*)(in + (size_t)r0 * D_MODEL);
    float4* r4 = (float4*)&rows[0][0];
#pragma unroll
    for (int t = 0; t < 8; ++t) r4[tid + 256 * t] = in4[tid + 256 * t];
  }
  __syncthreads();
  const int lane = tid & 63;
  const int wv = tid >> 6;        // 0..3
  const int rglob = r0 + wv * 4;  // wave's first global row (mult of 4)
  const float* __restrict__ Wl = W + lane;
  float c0[4] = {0.f, 0.f, 0.f, 0.f}, c1[4] = {0.f, 0.f, 0.f, 0.f};
#pragma unroll 4
  for (int e = 0; e < D_MODEL; e += 4) {
    float w0 = Wl[(size_t)(e + 0) * DK];
    float w1 = Wl[(size_t)(e + 1) * DK];
    float w2 = Wl[(size_t)(e + 2) * DK];
    float w3 = Wl[(size_t)(e + 3) * DK];
#pragma unroll
    for (int r = 0; r < 4; ++r) {
      float4 x = *(const float4*)&rows[wv * 4 + r][e];
      c0[r] = fmaf(x.x, w0, c0[r]);
      c1[r] = fmaf(x.y, w1, c1[r]);
      c0[r] = fmaf(x.z, w2, c0[r]);
      c1[r] = fmaf(x.w, w3, c1[r]);
    }
  }
  float acc[4];
#pragma unroll
  for (int r = 0; r < 4; ++r) acc[r] = c0[r] + c1[r];
  if (type == 0) {
    float vpar = v_param[lane];
#pragma unroll
    for (int r = 0; r < 4; ++r) {
      float iv = __builtin_amdgcn_exp2f(-L2E2 * acc[r]);
      float A = vpar * iv, B = iv;
      float Ah = __shfl_down(A, 32);  // lane d gets A_{d+32}
      float Bh = __shfl_down(B, 32);
      if (lane < 32)
        ab4[(size_t)(rglob + r) * 32 + lane] = make_float4(A, B, Ah, Bh);
    }
  } else if (type == 1) {
    float e4[4], h4[4];
#pragma unroll
    for (int r = 0; r < 4; ++r) {
      e4[r] = __builtin_amdgcn_exp2f(L2E2 * acc[r]);
      h4[r] = __shfl_down(e4[r], 32);  // lane d gets Ek[d+32]
    }
    if (lane < 32) {
      int b = rglob >> 10, j0 = rglob & 1023;  // rglob%4==0 -> 16B aligned
      float2* bp = ekT2 + (size_t)b * 32 * LK + (size_t)lane * LK + j0;
      *(float4*)bp = make_float4(e4[0], h4[0], e4[1], h4[1]);
      *(float4*)(bp + 2) = make_float4(e4[2], h4[2], e4[3], h4[3]);
    }
  } else {
#pragma unroll
    for (int r = 0; r < 4; ++r) vp[(size_t)(rglob + r) * DK + lane] = acc[r];
  }
}

// ---------------- fused scores + softmax + PV + FC + LN ----------------
// r13-proven (53.9us): 256 thr (4 waves), RB=4 rows/block, grid 512.
// Score: zero LDS, wave-uniform A/B s_loads, quad-rcp, f32 K, strided
// 4 j per thread (tid + jj*256).
#define RB 4
__global__ __launch_bounds__(256, 4) void attn_kernel(
    const float4* __restrict__ ab4, const float2* __restrict__ ekT2,
    const float* __restrict__ vp, const float* __restrict__ resid,
    const float* __restrict__ Wfc, const float* __restrict__ gamma,
    const float* __restrict__ beta, float* __restrict__ out,
    float* __restrict__ attn_out) {
  __shared__ float sc[RB][LK];                  // 16 KB P rows
  __shared__ float4 pvred[4][RB][16];           // 4 KB PV partials
  __shared__ __align__(16) float ovlT[DK][RB];  // 1 KB, e-major
  __shared__ float red[2][RB][4];               // LN reductions
  __shared__ float mred[RB][4], sred[RB][4];
  const int tid = threadIdx.x;
  const int row0 = blockIdx.x * RB;  // RB | LQ -> single batch per block
  const int batch = row0 >> 10;
  const float2* __restrict__ ekT_b = ekT2 + (size_t)batch * 32 * LK + tid;
  const float* __restrict__ vp_b = vp + (size_t)batch * LK * DK;
  const float4* __restrict__ abr0 = ab4 + (size_t)(row0 + 0) * 32;
  const float4* __restrict__ abr1 = ab4 + (size_t)(row0 + 1) * 32;
  const float4* __restrict__ abr2 = ab4 + (size_t)(row0 + 2) * 32;
  const float4* __restrict__ abr3 = ab4 + (size_t)(row0 + 3) * 32;

  float a0[4] = {0.f, 0.f, 0.f, 0.f};  // [jj] row 0, static-indexed
  float a1[4] = {0.f, 0.f, 0.f, 0.f};
  float a2[4] = {0.f, 0.f, 0.f, 0.f};
  float a3[4] = {0.f, 0.f, 0.f, 0.f};

#pragma unroll
  for (int qd = 0; qd < 16; ++qd) {  // quad covers dp = 2qd, 2qd+1
    float2 k0[4], k1[4];
#pragma unroll
    for (int jj = 0; jj < 4; ++jj) {
      k0[jj] = ekT_b[(size_t)(2 * qd + 0) * LK + jj * 256];
      k1[jj] = ekT_b[(size_t)(2 * qd + 1) * LK + jj * 256];
    }
    // wave-uniform A/B loads (no tid in address -> scalarized)
    float4 P0 = abr0[2 * qd], Q0 = abr0[2 * qd + 1];
    float4 P1 = abr1[2 * qd], Q1 = abr1[2 * qd + 1];
    float4 P2 = abr2[2 * qd], Q2 = abr2[2 * qd + 1];
    float4 P3 = abr3[2 * qd], Q3 = abr3[2 * qd + 1];
#pragma unroll
    for (int jj = 0; jj < 4; ++jj) {
#define QUAD(PP, QQ, ACC)                                                  \
  {                                                                        \
    float x1 = k0[jj].x + PP.y, x2 = k0[jj].y + PP.w;                      \
    float x3 = k1[jj].x + QQ.y, x4 = k1[jj].y + QQ.w;                      \
    float p12 = x1 * x2, p34 = x3 * x4;                                    \
    float n12 = fmaf(PP.z, x1, PP.x * x2);                                 \
    float n34 = fmaf(QQ.z, x3, QQ.x * x4);                                 \
    float num = fmaf(n34, p12, n12 * p34);                                 \
    ACC[jj] = fmaf(num, __builtin_amdgcn_rcpf(p12 * p34), ACC[jj]);        \
  }
      QUAD(P0, Q0, a0)
      QUAD(P1, Q1, a1)
      QUAD(P2, Q2, a2)
      QUAD(P3, Q3, a3)
#undef QUAD
    }
  }

  const int wave = __builtin_amdgcn_readfirstlane(tid >> 6);
  const int lane = tid & 63;

  // softmax over score = C - 2*acc -> shift by min(acc); all waves, 4 rows
  {
    float pm0 = fminf(fminf(a0[0], a0[1]), fminf(a0[2], a0[3]));
    float pm1 = fminf(fminf(a1[0], a1[1]), fminf(a1[2], a1[3]));
    float pm2 = fminf(fminf(a2[0], a2[1]), fminf(a2[2], a2[3]));
    float pm3 = fminf(fminf(a3[0], a3[1]), fminf(a3[2], a3[3]));
#pragma unroll
    for (int off = 32; off > 0; off >>= 1) {
      pm0 = fminf(pm0, __shfl_xor(pm0, off));
      pm1 = fminf(pm1, __shfl_xor(pm1, off));
      pm2 = fminf(pm2, __shfl_xor(pm2, off));
      pm3 = fminf(pm3, __shfl_xor(pm3, off));
    }
    if (lane == 0) {
      mred[0][wave] = pm0; mred[1][wave] = pm1;
      mred[2][wave] = pm2; mred[3][wave] = pm3;
    }
    __syncthreads();
    float m0 = fminf(fminf(mred[0][0], mred[0][1]), fminf(mred[0][2], mred[0][3]));
    float m1 = fminf(fminf(mred[1][0], mred[1][1]), fminf(mred[1][2], mred[1][3]));
    float m2 = fminf(fminf(mred[2][0], mred[2][1]), fminf(mred[2][2], mred[2][3]));
    float m3 = fminf(fminf(mred[3][0], mred[3][1]), fminf(mred[3][2], mred[3][3]));
    float s0 = 0.f, s1 = 0.f, s2 = 0.f, s3 = 0.f;
#pragma unroll
    for (int jj = 0; jj < 4; ++jj) {
      a0[jj] = __builtin_amdgcn_exp2f((m0 - a0[jj]) * L2E2); s0 += a0[jj];
      a1[jj] = __builtin_amdgcn_exp2f((m1 - a1[jj]) * L2E2); s1 += a1[jj];
      a2[jj] = __builtin_amdgcn_exp2f((m2 - a2[jj]) * L2E2); s2 += a2[jj];
      a3[jj] = __builtin_amdgcn_exp2f((m3 - a3[jj]) * L2E2); s3 += a3[jj];
    }
#pragma unroll
    for (int off = 32; off > 0; off >>= 1) {
      s0 += __shfl_xor(s0, off); s1 += __shfl_xor(s1, off);
      s2 += __shfl_xor(s2, off); s3 += __shfl_xor(s3, off);
    }
    if (lane == 0) {
      sred[0][wave] = s0; sred[1][wave] = s1;
      sred[2][wave] = s2; sred[3][wave] = s3;
    }
    __syncthreads();
    float i0 = __builtin_amdgcn_rcpf(sred[0][0] + sred[0][1] + sred[0][2] + sred[0][3]);
    float i1 = __builtin_amdgcn_rcpf(sred[1][0] + sred[1][1] + sred[1][2] + sred[1][3]);
    float i2 = __builtin_amdgcn_rcpf(sred[2][0] + sred[2][1] + sred[2][2] + sred[2][3]);
    float i3 = __builtin_amdgcn_rcpf(sred[3][0] + sred[3][1] + sred[3][2] + sred[3][3]);
    float* __restrict__ ar0 = attn_out + (size_t)(row0 + 0) * LK;
    float* __restrict__ ar1 = attn_out + (size_t)(row0 + 1) * LK;
    float* __restrict__ ar2 = attn_out + (size_t)(row0 + 2) * LK;
    float* __restrict__ ar3 = attn_out + (size_t)(row0 + 3) * LK;
#pragma unroll
    for (int jj = 0; jj < 4; ++jj) {
      float p0 = a0[jj] * i0, p1 = a1[jj] * i1;
      float p2 = a2[jj] * i2, p3 = a3[jj] * i3;
      sc[0][tid + jj * 256] = p0; ar0[tid + jj * 256] = p0;
      sc[1][tid + jj * 256] = p1; ar1[tid + jj * 256] = p1;
      sc[2][tid + jj * 256] = p2; ar2[tid + jj * 256] = p2;
      sc[3][tid + jj * 256] = p3; ar3[tid + jj * 256] = p3;
    }
  }
  __syncthreads();

  // PV: wave owns 256-j slice; vp read once per block per j (serves 4 rows)
  {
    const int jj = lane >> 4, l16 = lane & 15;
    const float4* __restrict__ vp4 = (const float4*)vp_b;
    float4 a[RB];
#pragma unroll
    for (int r = 0; r < RB; ++r) a[r] = make_float4(0.f, 0.f, 0.f, 0.f);
#pragma unroll 4
    for (int it = 0; it < 64; ++it) {
      int j = (wave << 8) + (it << 2) + jj;
      float4 vv = vp4[(size_t)j * (DK / 4) + l16];
#pragma unroll
      for (int r = 0; r < RB; ++r) {
        float pw = sc[r][j];
        a[r].x = fmaf(pw, vv.x, a[r].x);
        a[r].y = fmaf(pw, vv.y, a[r].y);
        a[r].z = fmaf(pw, vv.z, a[r].z);
        a[r].w = fmaf(pw, vv.w, a[r].w);
      }
    }
#pragma unroll
    for (int r = 0; r < RB; ++r) {
      a[r].x += __shfl_xor(a[r].x, 16); a[r].y += __shfl_xor(a[r].y, 16);
      a[r].z += __shfl_xor(a[r].z, 16); a[r].w += __shfl_xor(a[r].w, 16);
      a[r].x += __shfl_xor(a[r].x, 32); a[r].y += __shfl_xor(a[r].y, 32);
      a[r].z += __shfl_xor(a[r].z, 32); a[r].w += __shfl_xor(a[r].w, 32);
    }
    if (jj == 0) {
#pragma unroll
      for (int r = 0; r < RB; ++r) pvred[wave][r][l16] = a[r];
    }
  }
  __syncthreads();
  if (tid < 64) {  // final PV reduce -> transposed ovlT[e][r]
    int r = tid >> 4, l16 = tid & 15;
    float4 s = make_float4(0.f, 0.f, 0.f, 0.f);
#pragma unroll
    for (int w = 0; w < 4; ++w) {
      float4 t = pvred[w][r][l16];
      s.x += t.x; s.y += t.y; s.z += t.z; s.w += t.w;
    }
    ovlT[l16 * 4 + 0][r] = s.x;
    ovlT[l16 * 4 + 1][r] = s.y;
    ovlT[l16 * 4 + 2][r] = s.z;
    ovlT[l16 * 4 + 3][r] = s.w;
  }
  __syncthreads();

  // FC + residual + LN: thread owns columns c, c+256 of 4 rows
  {
    const int c0 = tid, c1 = tid + 256;
    float y[RB][2];
#pragma unroll
    for (int r = 0; r < RB; ++r) {
      y[r][0] = resid[(size_t)(row0 + r) * D_MODEL + c0];
      y[r][1] = resid[(size_t)(row0 + r) * D_MODEL + c1];
    }
#pragma unroll 4
    for (int e = 0; e < DK; ++e) {
      float w0 = Wfc[(size_t)e * D_MODEL + c0];
      float w1 = Wfc[(size_t)e * D_MODEL + c1];
      float4 ov = *(const float4*)&ovlT[e][0];
      y[0][0] = fmaf(ov.x, w0, y[0][0]); y[0][1] = fmaf(ov.x, w1, y[0][1]);
      y[1][0] = fmaf(ov.y, w0, y[1][0]); y[1][1] = fmaf(ov.y, w1, y[1][1]);
      y[2][0] = fmaf(ov.z, w0, y[2][0]); y[2][1] = fmaf(ov.z, w1, y[2][1]);
      y[3][0] = fmaf(ov.w, w0, y[3][0]); y[3][1] = fmaf(ov.w, w1, y[3][1]);
    }
#pragma unroll
    for (int r = 0; r < RB; ++r) {
      float s = y[r][0] + y[r][1];
#pragma unroll
      for (int off = 32; off > 0; off >>= 1) s += __shfl_xor(s, off);
      if (lane == 0) red[0][r][wave] = s;
    }
    __syncthreads();
    float mu[RB];
#pragma unroll
    for (int r = 0; r < RB; ++r)
      mu[r] = (red[0][r][0] + red[0][r][1] + red[0][r][2] + red[0][r][3]) *
              (1.0f / D_MODEL);
#pragma unroll
    for (int r = 0; r < RB; ++r) {
      float d0 = y[r][0] - mu[r], d1 = y[r][1] - mu[r];
      float s = d0 * d0 + d1 * d1;
#pragma unroll
      for (int off = 32; off > 0; off >>= 1) s += __shfl_xor(s, off);
      if (lane == 0) red[1][r][wave] = s;
    }
    __syncthreads();
    float g0 = gamma[c0], g1 = gamma[c1], b0 = beta[c0], b1 = beta[c1];
#pragma unroll
    for (int r = 0; r < RB; ++r) {
      float var = (red[1][r][0] + red[1][r][1] + red[1][r][2] + red[1][r][3]) *
                  (1.0f / D_MODEL);
      float rstd = rsqrtf(var + LN_EPS);
      out[(size_t)(row0 + r) * D_MODEL + c0] = (y[r][0] - mu[r]) * rstd * g0 + b0;
      out[(size_t)(row0 + r) * D_MODEL + c1] = (y[r][1] - mu[r]) * rstd * g1 + b1;
    }
  }
}

extern "C" void kernel_launch(void* const* d_in, const int* in_sizes, int n_in,
                              void* d_out, int out_size, void* d_ws,
                              size_t ws_size, hipStream_t stream) {
  const float* q = (const float*)d_in[0];
  const float* k = (const float*)d_in[1];
  const float* v = (const float*)d_in[2];
  const float* Wq = (const float*)d_in[3];
  const float* Wk = (const float*)d_in[4];
  const float* Wv = (const float*)d_in[5];
  const float* v_param = (const float*)d_in[6];
  const float* Wfc = (const float*)d_in[7];
  const float* gamma = (const float*)d_in[8];
  const float* beta = (const float*)d_in[9];

  float* out = (float*)d_out;                     // [B*LQ*D_MODEL]
  float* attn = out + (size_t)NB * LQ * D_MODEL;  // [B*LQ*LK]

  float* base = (float*)d_ws;
  float4* ab4 = (float4*)base;                    // 2048*32 float4 (1 MB)
  float* p1 = base + (size_t)NB * LQ * 32 * 4;    // floats consumed by ab4
  float2* ekT2 = (float2*)p1;                     // 2*32*1024 float2 (512 KB)
  float* vp = p1 + (size_t)NB * 32 * LK * 2;      // [2048*64]

  hipLaunchKernelGGL(proj_kernel, dim3(3 * 128), dim3(256), 0, stream, q, k, v,
                     Wq, Wk, Wv, v_param, ab4, ekT2, vp);
  hipLaunchKernelGGL(attn_kernel, dim3(NB * LQ / RB), dim3(256), 0, stream,
                     ab4, ekT2, vp, q, Wfc, gamma, beta, out, attn);
}

// Round 20
// 54.773 us; speedup vs baseline: 1.1516x; 1.0041x over previous
//
#include <hip/hip_runtime.h>
#include <cstddef>
#include <cstdint>

#define D_MODEL 512
#define DK 64
#define LQ 1024
#define LK 1024
#define NB 2
#define LN_EPS 1e-6f
#define L2E2 2.8853900817779268f  // 2*log2(e)

// ---------------- projections ---------------- (r13 shape; new K layout)
// type 0: qp=q@Wq -> ab4[row][dp] = float4{A_dp, B_dp, A_dp+32, B_dp+32}
//         with A = v_d*e^{-2qp}, B = e^{-2qp}
// type 1: ek=e^{2*(k@Wk)} -> ekT3[b][jg][dp][{lo4,hi4}]:
//         per j-group of 4, all 32 dp packed in 1 KB so the attn score
//         loop reads its whole K working set from ONE base pointer with
//         compile-time immediate offsets (kills per-load address VALU).
// type 2: vp = v@Wv (f32 row-major)
#define PR_ROWS 16
__global__ __launch_bounds__(256, 4) void proj_kernel(
    const float* __restrict__ q, const float* __restrict__ k,
    const float* __restrict__ v, const float* __restrict__ Wq,
    const float* __restrict__ Wk, const float* __restrict__ Wv,
    const float* __restrict__ v_param, float4* __restrict__ ab4,
    float* __restrict__ ekT3, float* __restrict__ vp) {
  __shared__ float rows[PR_ROWS][D_MODEL];  // 32 KB
  const int tid = threadIdx.x;
  const int type = blockIdx.x >> 7;  // 128 row-groups per type
  const int r0 = (blockIdx.x & 127) * PR_ROWS;
  const float* __restrict__ in = (type == 0) ? q : (type == 1) ? k : v;
  const float* __restrict__ W = (type == 0) ? Wq : (type == 1) ? Wk : Wv;
  {
    const float4* __restrict__ in4 = (const float4*)(in + (size_t)r0 * D_MODEL);
    float4* r4 = (float4*)&rows[0][0];
#pragma unroll
    for (int t = 0; t < 8; ++t) r4[tid + 256 * t] = in4[tid + 256 * t];
  }
  __syncthreads();
  const int lane = tid & 63;
  const int wv = tid >> 6;        // 0..3
  const int rglob = r0 + wv * 4;  // wave's first global row (mult of 4)
  const float* __restrict__ Wl = W + lane;
  float c0[4] = {0.f, 0.f, 0.f, 0.f}, c1[4] = {0.f, 0.f, 0.f, 0.f};
#pragma unroll 4
  for (int e = 0; e < D_MODEL; e += 4) {
    float w0 = Wl[(size_t)(e + 0) * DK];
    float w1 = Wl[(size_t)(e + 1) * DK];
    float w2 = Wl[(size_t)(e + 2) * DK];
    float w3 = Wl[(size_t)(e + 3) * DK];
#pragma unroll
    for (int r = 0; r < 4; ++r) {
      float4 x = *(const float4*)&rows[wv * 4 + r][e];
      c0[r] = fmaf(x.x, w0, c0[r]);
      c1[r] = fmaf(x.y, w1, c1[r]);
      c0[r] = fmaf(x.z, w2, c0[r]);
      c1[r] = fmaf(x.w, w3, c1[r]);
    }
  }
  float acc[4];
#pragma unroll
  for (int r = 0; r < 4; ++r) acc[r] = c0[r] + c1[r];
  if (type == 0) {
    float vpar = v_param[lane];
#pragma unroll
    for (int r = 0; r < 4; ++r) {
      float iv = __builtin_amdgcn_exp2f(-L2E2 * acc[r]);
      float A = vpar * iv, B = iv;
      float Ah = __shfl_down(A, 32);  // lane d gets A_{d+32}
      float Bh = __shfl_down(B, 32);
      if (lane < 32)
        ab4[(size_t)(rglob + r) * 32 + lane] = make_float4(A, B, Ah, Bh);
    }
  } else if (type == 1) {
    float e4[4], h4[4];
#pragma unroll
    for (int r = 0; r < 4; ++r) {
      e4[r] = __builtin_amdgcn_exp2f(L2E2 * acc[r]);
      h4[r] = __shfl_down(e4[r], 32);  // lane d gets Ek[d+32]
    }
    if (lane < 32) {
      // group g = rglob/4 (rows rglob..rglob+3 ARE the group's 4 j-slots)
      int b = rglob >> 10, g = (rglob & 1023) >> 2;
      float* bp = ekT3 + (size_t)b * 65536 + (size_t)g * 256 + lane * 8;
      *(float4*)bp = make_float4(e4[0], e4[1], e4[2], e4[3]);        // lo4
      *(float4*)(bp + 4) = make_float4(h4[0], h4[1], h4[2], h4[3]);  // hi4
    }
  } else {
#pragma unroll
    for (int r = 0; r < 4; ++r) vp[(size_t)(rglob + r) * DK + lane] = acc[r];
  }
}

// ---------------- fused scores + softmax + PV + FC + LN ----------------
// r13 structure (256 thr, RB=4, grid 512); score loop reads K from the
// group-tiled layout: one base pointer per thread, 64 dwordx4 loads all at
// immediate offsets 0..1008 (zero per-load address VALU). Consecutive-j
// (r15-proven-neutral mapping); scalar quad-rcp math.
#define RB 4
__global__ __launch_bounds__(256, 4) void attn_kernel(
    const float4* __restrict__ ab4, const float* __restrict__ ekT3,
    const float* __restrict__ vp, const float* __restrict__ resid,
    const float* __restrict__ Wfc, const float* __restrict__ gamma,
    const float* __restrict__ beta, float* __restrict__ out,
    float* __restrict__ attn_out) {
  __shared__ float sc[RB][LK];                  // 16 KB P rows
  __shared__ float4 pvred[4][RB][16];           // 4 KB PV partials
  __shared__ __align__(16) float ovlT[DK][RB];  // 1 KB, e-major
  __shared__ float red[2][RB][4];               // LN reductions
  __shared__ float mred[RB][4], sred[RB][4];
  const int tid = threadIdx.x;
  const int row0 = blockIdx.x * RB;  // RB | LQ -> single batch per block
  const int batch = row0 >> 10;
  // thread's 1 KB K-tile: groups match j = 4*tid..4*tid+3
  const float* __restrict__ ekg =
      ekT3 + (size_t)batch * 65536 + (size_t)tid * 256;
  const float* __restrict__ vp_b = vp + (size_t)batch * LK * DK;
  const float4* __restrict__ abr0 = ab4 + (size_t)(row0 + 0) * 32;
  const float4* __restrict__ abr1 = ab4 + (size_t)(row0 + 1) * 32;
  const float4* __restrict__ abr2 = ab4 + (size_t)(row0 + 2) * 32;
  const float4* __restrict__ abr3 = ab4 + (size_t)(row0 + 3) * 32;

  float a0[4] = {0.f, 0.f, 0.f, 0.f};  // [jj] per row, static-indexed
  float a1[4] = {0.f, 0.f, 0.f, 0.f};
  float a2[4] = {0.f, 0.f, 0.f, 0.f};
  float a3[4] = {0.f, 0.f, 0.f, 0.f};

#pragma unroll
  for (int qd = 0; qd < 16; ++qd) {  // quad covers dp = 2qd, 2qd+1
    const int dp0 = 2 * qd, dp1 = 2 * qd + 1;
    // 4 loads, ALL at immediate offsets from ekg + tid*1KB
    float4 lo0 = *(const float4*)(ekg + dp0 * 8);
    float4 hi0 = *(const float4*)(ekg + dp0 * 8 + 4);
    float4 lo1 = *(const float4*)(ekg + dp1 * 8);
    float4 hi1 = *(const float4*)(ekg + dp1 * 8 + 4);
    float k0lo[4] = {lo0.x, lo0.y, lo0.z, lo0.w};
    float k0hi[4] = {hi0.x, hi0.y, hi0.z, hi0.w};
    float k1lo[4] = {lo1.x, lo1.y, lo1.z, lo1.w};
    float k1hi[4] = {hi1.x, hi1.y, hi1.z, hi1.w};
    // wave-uniform A/B loads (no tid in address -> scalarized s_loads)
    float4 P0 = abr0[dp0], Q0 = abr0[dp1];
    float4 P1 = abr1[dp0], Q1 = abr1[dp1];
    float4 P2 = abr2[dp0], Q2 = abr2[dp1];
    float4 P3 = abr3[dp0], Q3 = abr3[dp1];
#pragma unroll
    for (int jj = 0; jj < 4; ++jj) {
#define QUAD(PP, QQ, ACC)                                                  \
  {                                                                        \
    float x1 = k0lo[jj] + PP.y, x2 = k0hi[jj] + PP.w;                      \
    float x3 = k1lo[jj] + QQ.y, x4 = k1hi[jj] + QQ.w;                      \
    float p12 = x1 * x2, p34 = x3 * x4;                                    \
    float n12 = fmaf(PP.z, x1, PP.x * x2);                                 \
    float n34 = fmaf(QQ.z, x3, QQ.x * x4);                                 \
    float num = fmaf(n34, p12, n12 * p34);                                 \
    ACC[jj] = fmaf(num, __builtin_amdgcn_rcpf(p12 * p34), ACC[jj]);        \
  }
      QUAD(P0, Q0, a0)
      QUAD(P1, Q1, a1)
      QUAD(P2, Q2, a2)
      QUAD(P3, Q3, a3)
#undef QUAD
    }
  }

  const int wave = __builtin_amdgcn_readfirstlane(tid >> 6);
  const int lane = tid & 63;

  // softmax over score = C - 2*acc -> shift by min(acc); all waves, 4 rows
  {
    float pm0 = fminf(fminf(a0[0], a0[1]), fminf(a0[2], a0[3]));
    float pm1 = fminf(fminf(a1[0], a1[1]), fminf(a1[2], a1[3]));
    float pm2 = fminf(fminf(a2[0], a2[1]), fminf(a2[2], a2[3]));
    float pm3 = fminf(fminf(a3[0], a3[1]), fminf(a3[2], a3[3]));
#pragma unroll
    for (int off = 32; off > 0; off >>= 1) {
      pm0 = fminf(pm0, __shfl_xor(pm0, off));
      pm1 = fminf(pm1, __shfl_xor(pm1, off));
      pm2 = fminf(pm2, __shfl_xor(pm2, off));
      pm3 = fminf(pm3, __shfl_xor(pm3, off));
    }
    if (lane == 0) {
      mred[0][wave] = pm0; mred[1][wave] = pm1;
      mred[2][wave] = pm2; mred[3][wave] = pm3;
    }
    __syncthreads();
    float m0 = fminf(fminf(mred[0][0], mred[0][1]), fminf(mred[0][2], mred[0][3]));
    float m1 = fminf(fminf(mred[1][0], mred[1][1]), fminf(mred[1][2], mred[1][3]));
    float m2 = fminf(fminf(mred[2][0], mred[2][1]), fminf(mred[2][2], mred[2][3]));
    float m3 = fminf(fminf(mred[3][0], mred[3][1]), fminf(mred[3][2], mred[3][3]));
    float s0 = 0.f, s1 = 0.f, s2 = 0.f, s3 = 0.f;
#pragma unroll
    for (int jj = 0; jj < 4; ++jj) {
      a0[jj] = __builtin_amdgcn_exp2f((m0 - a0[jj]) * L2E2); s0 += a0[jj];
      a1[jj] = __builtin_amdgcn_exp2f((m1 - a1[jj]) * L2E2); s1 += a1[jj];
      a2[jj] = __builtin_amdgcn_exp2f((m2 - a2[jj]) * L2E2); s2 += a2[jj];
      a3[jj] = __builtin_amdgcn_exp2f((m3 - a3[jj]) * L2E2); s3 += a3[jj];
    }
#pragma unroll
    for (int off = 32; off > 0; off >>= 1) {
      s0 += __shfl_xor(s0, off); s1 += __shfl_xor(s1, off);
      s2 += __shfl_xor(s2, off); s3 += __shfl_xor(s3, off);
    }
    if (lane == 0) {
      sred[0][wave] = s0; sred[1][wave] = s1;
      sred[2][wave] = s2; sred[3][wave] = s3;
    }
    __syncthreads();
    float i0 = __builtin_amdgcn_rcpf(sred[0][0] + sred[0][1] + sred[0][2] + sred[0][3]);
    float i1 = __builtin_amdgcn_rcpf(sred[1][0] + sred[1][1] + sred[1][2] + sred[1][3]);
    float i2 = __builtin_amdgcn_rcpf(sred[2][0] + sred[2][1] + sred[2][2] + sred[2][3]);
    float i3 = __builtin_amdgcn_rcpf(sred[3][0] + sred[3][1] + sred[3][2] + sred[3][3]);
    // consecutive-j: one float4 store per row into sc and attn_out
    float4 p0 = make_float4(a0[0] * i0, a0[1] * i0, a0[2] * i0, a0[3] * i0);
    float4 p1 = make_float4(a1[0] * i1, a1[1] * i1, a1[2] * i1, a1[3] * i1);
    float4 p2 = make_float4(a2[0] * i2, a2[1] * i2, a2[2] * i2, a2[3] * i2);
    float4 p3 = make_float4(a3[0] * i3, a3[1] * i3, a3[2] * i3, a3[3] * i3);
    *(float4*)&sc[0][4 * tid] = p0;
    *(float4*)&sc[1][4 * tid] = p1;
    *(float4*)&sc[2][4 * tid] = p2;
    *(float4*)&sc[3][4 * tid] = p3;
    *(float4*)(attn_out + (size_t)(row0 + 0) * LK + 4 * tid) = p0;
    *(float4*)(attn_out + (size_t)(row0 + 1) * LK + 4 * tid) = p1;
    *(float4*)(attn_out + (size_t)(row0 + 2) * LK + 4 * tid) = p2;
    *(float4*)(attn_out + (size_t)(row0 + 3) * LK + 4 * tid) = p3;
  }
  __syncthreads();

  // PV: wave owns 256-j slice; vp read once per block per j (serves 4 rows)
  {
    const int jj = lane >> 4, l16 = lane & 15;
    const float4* __restrict__ vp4 = (const float4*)vp_b;
    float4 a[RB];
#pragma unroll
    for (int r = 0; r < RB; ++r) a[r] = make_float4(0.f, 0.f, 0.f, 0.f);
#pragma unroll 4
    for (int it = 0; it < 64; ++it) {
      int j = (wave << 8) + (it << 2) + jj;
      float4 vv = vp4[(size_t)j * (DK / 4) + l16];
#pragma unroll
      for (int r = 0; r < RB; ++r) {
        float pw = sc[r][j];
        a[r].x = fmaf(pw, vv.x, a[r].x);
        a[r].y = fmaf(pw, vv.y, a[r].y);
        a[r].z = fmaf(pw, vv.z, a[r].z);
        a[r].w = fmaf(pw, vv.w, a[r].w);
      }
    }
#pragma unroll
    for (int r = 0; r < RB; ++r) {
      a[r].x += __shfl_xor(a[r].x, 16); a[r].y += __shfl_xor(a[r].y, 16);
      a[r].z += __shfl_xor(a[r].z, 16); a[r].w += __shfl_xor(a[r].w, 16);
      a[r].x += __shfl_xor(a[r].x, 32); a[r].y += __shfl_xor(a[r].y, 32);
      a[r].z += __shfl_xor(a[r].z, 32); a[r].w += __shfl_xor(a[r].w, 32);
    }
    if (jj == 0) {
#pragma unroll
      for (int r = 0; r < RB; ++r) pvred[wave][r][l16] = a[r];
    }
  }
  __syncthreads();
  if (tid < 64) {  // final PV reduce -> transposed ovlT[e][r]
    int r = tid >> 4, l16 = tid & 15;
    float4 s = make_float4(0.f, 0.f, 0.f, 0.f);
#pragma unroll
    for (int w = 0; w < 4; ++w) {
      float4 t = pvred[w][r][l16];
      s.x += t.x; s.y += t.y; s.z += t.z; s.w += t.w;
    }
    ovlT[l16 * 4 + 0][r] = s.x;
    ovlT[l16 * 4 + 1][r] = s.y;
    ovlT[l16 * 4 + 2][r] = s.z;
    ovlT[l16 * 4 + 3][r] = s.w;
  }
  __syncthreads();

  // FC + residual + LN: thread owns columns c, c+256 of 4 rows
  {
    const int c0 = tid, c1 = tid + 256;
    float y[RB][2];
#pragma unroll
    for (int r = 0; r < RB; ++r) {
      y[r][0] = resid[(size_t)(row0 + r) * D_MODEL + c0];
      y[r][1] = resid[(size_t)(row0 + r) * D_MODEL + c1];
    }
#pragma unroll 4
    for (int e = 0; e < DK; ++e) {
      float w0 = Wfc[(size_t)e * D_MODEL + c0];
      float w1 = Wfc[(size_t)e * D_MODEL + c1];
      float4 ov = *(const float4*)&ovlT[e][0];
      y[0][0] = fmaf(ov.x, w0, y[0][0]); y[0][1] = fmaf(ov.x, w1, y[0][1]);
      y[1][0] = fmaf(ov.y, w0, y[1][0]); y[1][1] = fmaf(ov.y, w1, y[1][1]);
      y[2][0] = fmaf(ov.z, w0, y[2][0]); y[2][1] = fmaf(ov.z, w1, y[2][1]);
      y[3][0] = fmaf(ov.w, w0, y[3][0]); y[3][1] = fmaf(ov.w, w1, y[3][1]);
    }
#pragma unroll
    for (int r = 0; r < RB; ++r) {
      float s = y[r][0] + y[r][1];
#pragma unroll
      for (int off = 32; off > 0; off >>= 1) s += __shfl_xor(s, off);
      if (lane == 0) red[0][r][wave] = s;
    }
    __syncthreads();
    float mu[RB];
#pragma unroll
    for (int r = 0; r < RB; ++r)
      mu[r] = (red[0][r][0] + red[0][r][1] + red[0][r][2] + red[0][r][3]) *
              (1.0f / D_MODEL);
#pragma unroll
    for (int r = 0; r < RB; ++r) {
      float d0 = y[r][0] - mu[r], d1 = y[r][1] - mu[r];
      float s = d0 * d0 + d1 * d1;
#pragma unroll
      for (int off = 32; off > 0; off >>= 1) s += __shfl_xor(s, off);
      if (lane == 0) red[1][r][wave] = s;
    }
    __syncthreads();
    float g0 = gamma[c0], g1 = gamma[c1], b0 = beta[c0], b1 = beta[c1];
#pragma unroll
    for (int r = 0; r < RB; ++r) {
      float var = (red[1][r][0] + red[1][r][1] + red[1][r][2] + red[1][r][3]) *
                  (1.0f / D_MODEL);
      float rstd = rsqrtf(var + LN_EPS);
      out[(size_t)(row0 + r) * D_MODEL + c0] = (y[r][0] - mu[r]) * rstd * g0 + b0;
      out[(size_t)(row0 + r) * D_MODEL + c1] = (y[r][1] - mu[r]) * rstd * g1 + b1;
    }
  }
}

extern "C" void kernel_launch(void* const* d_in, const int* in_sizes, int n_in,
                              void* d_out, int out_size, void* d_ws,
                              size_t ws_size, hipStream_t stream) {
  const float* q = (const float*)d_in[0];
  const float* k = (const float*)d_in[1];
  const float* v = (const float*)d_in[2];
  const float* Wq = (const float*)d_in[3];
  const float* Wk = (const float*)d_in[4];
  const float* Wv = (const float*)d_in[5];
  const float* v_param = (const float*)d_in[6];
  const float* Wfc = (const float*)d_in[7];
  const float* gamma = (const float*)d_in[8];
  const float* beta = (const float*)d_in[9];

  float* out = (float*)d_out;                     // [B*LQ*D_MODEL]
  float* attn = out + (size_t)NB * LQ * D_MODEL;  // [B*LQ*LK]

  float* base = (float*)d_ws;
  float4* ab4 = (float4*)base;                     // 2048*32 float4 (1 MB)
  float* ekT3 = base + (size_t)NB * LQ * 32 * 4;   // [2*65536] (512 KB)
  float* vp = ekT3 + (size_t)NB * 65536;           // [2048*64]

  hipLaunchKernelGGL(proj_kernel, dim3(3 * 128), dim3(256), 0, stream, q, k, v,
                     Wq, Wk, Wv, v_param, ab4, ekT3, vp);
  hipLaunchKernelGGL(attn_kernel, dim3(NB * LQ / RB), dim3(256), 0, stream,
                     ab4, ekT3, vp, q, Wfc, gamma, beta, out, attn);
}